// Round 2
// baseline (727.702 us; speedup 1.0000x reference)
//
#include <hip/hip_runtime.h>
#include <hip/hip_bf16.h>

#define BB 512
#define TT 512
#define HH 100
#define DI 101
#define DOUT 2
#define BT (BB * TT)

typedef float f4 __attribute__((ext_vector_type(4)));

// ---------------------------------------------------------------------------
// Kernel 1: xp[r, c] = dot(in[r, :101], Wx[c, :101]) + b[c]   (unchanged)
// ---------------------------------------------------------------------------
__global__ __launch_bounds__(128, 2) void k_inproj(
    const float* __restrict__ in, const float* __restrict__ Wx,
    const float* __restrict__ bias, float* __restrict__ xp) {
  const int t = threadIdx.x;
  const int p = t >> 1;    // pair id 0..63
  const int kh = t & 1;    // k half
  const int c0 = p;        // always < 100
  const int c1 = p + 64;
  const bool c1ok = (c1 < HH);

  __shared__ __align__(16) float Atile[64 * 104];

  float4 wx0[13], wx1[13];
  {
    const float* w0 = Wx + (size_t)c0 * DI + kh * 52;
    const float* w1 = Wx + (size_t)(c1ok ? c1 : 0) * DI + kh * 52;
    const int nk = kh ? 49 : 52;
#pragma unroll
    for (int j = 0; j < 13; ++j) {
      float a0 = (4 * j + 0 < nk) ? w0[4 * j + 0] : 0.f;
      float a1 = (4 * j + 1 < nk) ? w0[4 * j + 1] : 0.f;
      float a2 = (4 * j + 2 < nk) ? w0[4 * j + 2] : 0.f;
      float a3 = (4 * j + 3 < nk) ? w0[4 * j + 3] : 0.f;
      wx0[j] = make_float4(a0, a1, a2, a3);
      float b0v = (4 * j + 0 < nk) ? w1[4 * j + 0] : 0.f;
      float b1v = (4 * j + 1 < nk) ? w1[4 * j + 1] : 0.f;
      float b2v = (4 * j + 2 < nk) ? w1[4 * j + 2] : 0.f;
      float b3v = (4 * j + 3 < nk) ? w1[4 * j + 3] : 0.f;
      wx1[j] = make_float4(b0v, b1v, b2v, b3v);
    }
  }
  const float bs0 = bias[c0];
  const float bs1 = c1ok ? bias[c1] : 0.f;

  const int row0 = blockIdx.x * 64;

  {
    const float* rp = in + (size_t)(row0 + p) * DI + kh * 52;
    float* dst = Atile + p * 104 + kh * 52;
#pragma unroll
    for (int j = 0; j < 52; ++j) {
      float v;
      if (kh == 0) v = rp[j];                       // k = j (<101)
      else        v = (52 + j < DI) ? rp[j] : 0.f;  // k = 52+j; pad 101..103=0
      dst[j] = v;
    }
  }
  __syncthreads();

#pragma unroll 2
  for (int r = 0; r < 64; ++r) {
    const float4* a4 = (const float4*)(Atile + r * 104 + kh * 52);
    float4 s0 = make_float4(0.f, 0.f, 0.f, 0.f);
    float4 s1 = make_float4(0.f, 0.f, 0.f, 0.f);
#pragma unroll
    for (int j = 0; j < 13; ++j) {
      float4 av = a4[j];
      s0.x = fmaf(av.x, wx0[j].x, s0.x);
      s0.y = fmaf(av.y, wx0[j].y, s0.y);
      s0.z = fmaf(av.z, wx0[j].z, s0.z);
      s0.w = fmaf(av.w, wx0[j].w, s0.w);
      s1.x = fmaf(av.x, wx1[j].x, s1.x);
      s1.y = fmaf(av.y, wx1[j].y, s1.y);
      s1.z = fmaf(av.z, wx1[j].z, s1.z);
      s1.w = fmaf(av.w, wx1[j].w, s1.w);
    }
    float p0 = (s0.x + s0.y) + (s0.z + s0.w);
    float p1 = (s1.x + s1.y) + (s1.z + s1.w);
    p0 += __shfl_xor(p0, 1, 64);
    p1 += __shfl_xor(p1, 1, 64);
    if (kh == 0) {
      float* xr = xp + (size_t)(row0 + r) * HH;
      xr[c0] = p0 + bs0;
      if (c1ok) xr[c1] = p1 + bs1;
    }
  }
}

// ---------------------------------------------------------------------------
// Kernel 2 (ROUND-1 REWRITE): barrier-free scan, one wave per batch.
//
// Old structure: 4 waves cooperate on one batch, k-split across lane pairs,
// s_barrier every step -> ~1480 cy/step (barrier rendezvous + cold-restart
// of the LDS->FMA chain + shuffle-reduce on the serial path).
//
// New structure: lane l (<50) owns states {2l, 2l+1} and computes the FULL
// 100-dot for both. No cross-lane reduce, no s_barrier. h lives in ONE
// 100-float LDS buffer per wave (uniform-address b128 broadcast reads,
// conflict-free). Wave-lockstep program order makes single-buffering safe:
// all step-t reads precede the step-t write; the DS pipe is in-order per
// wave and the compiler inserts the lgkm wait for the aliasing read.
// Weights: 50xfloat4 = 200 VGPR (launch_bounds(64,1) gives the allocator
// headroom; occupancy is irrelevant at 512 waves / 2 per CU).
// FMA stream uses ext_vector fma so the backend can pair v_pk_fma_f32.
// Output projection (DO=2) is FUSED here: 4 FMAs + 6-level shfl_xor tree
// per step, off the state chain -> k_outproj deleted.
// ---------------------------------------------------------------------------
__global__ __launch_bounds__(64, 1) void k_scan(
    const float* __restrict__ noise, const float* __restrict__ Wh,
    const float* __restrict__ ah0, const float* __restrict__ Wy,
    float* __restrict__ out, float* hstore /* aliases xp staging */) {
  const int b = blockIdx.x;
  const int l = threadIdx.x;   // 0..63
  const bool act = (l < 50);
  const int s0 = act ? 2 * l : 0;  // clamped state-pair base

  __shared__ __align__(16) float h_lds[HH];  // 100 floats = 25 float4 exactly

  // --- weights: rows s0, s0+1 (row = 400 B, 16B-aligned) ---
  f4 w0[25], w1[25];
  {
    const f4* r0 = (const f4*)(Wh + (size_t)s0 * HH);
    const f4* r1 = (const f4*)(Wh + (size_t)(s0 + 1) * HH);
#pragma unroll
    for (int j = 0; j < 25; ++j) {
      w0[j] = r0[j];
      w1[j] = r1[j];
    }
  }
  float wy00 = 0.f, wy01 = 0.f, wy10 = 0.f, wy11 = 0.f;
  if (act) {
    float2 wa = *(const float2*)(Wy + s0);        // Wy[0][s0..s0+1]
    float2 wb = *(const float2*)(Wy + HH + s0);   // Wy[1][s0..s0+1]
    wy00 = wa.x; wy01 = wa.y; wy10 = wb.x; wy11 = wb.y;
  }

  float ahx = 0.f, ahy = 0.f;
  if (act) {
    float2 a = *(const float2*)(ah0 + s0);
    ahx = a.x; ahy = a.y;
  }
  // initial h = retanh(ah0), no noise
  {
    float e0 = __expf(-2.f * ahx);
    float e1 = __expf(-2.f * ahy);
    float h0 = (ahx > 0.f) ? (1.f - e0) * __builtin_amdgcn_rcpf(1.f + e0) : 0.f;
    float h1 = (ahy > 0.f) ? (1.f - e1) * __builtin_amdgcn_rcpf(1.f + e1) : 0.f;
    if (act) *(float2*)&h_lds[s0] = make_float2(h0, h1);
  }

  const float* xp_base = hstore;  // in-place staging from k_inproj
  const size_t bbase = (size_t)b * TT * HH;
  float2* out2 = (float2*)out;

  // 4-deep prefetch (float2 per array per step; inactive lanes load nothing)
  float2 xpA = make_float2(0.f, 0.f), nzA = xpA;
  float2 xpB = xpA, nzB = xpA, xpC = xpA, nzC = xpA, xpD = xpA, nzD = xpA;
  if (act) {
    xpA = *(const float2*)(xp_base + bbase + (size_t)0 * HH + s0);
    nzA = *(const float2*)(noise + bbase + (size_t)0 * HH + s0);
    xpB = *(const float2*)(xp_base + bbase + (size_t)1 * HH + s0);
    nzB = *(const float2*)(noise + bbase + (size_t)1 * HH + s0);
    xpC = *(const float2*)(xp_base + bbase + (size_t)2 * HH + s0);
    nzC = *(const float2*)(noise + bbase + (size_t)2 * HH + s0);
    xpD = *(const float2*)(xp_base + bbase + (size_t)3 * HH + s0);
    nzD = *(const float2*)(noise + bbase + (size_t)3 * HH + s0);
  }

#define STEP(XP, NZ, tc)                                                      \
  {                                                                           \
    const int tpf = (tc) + 4;                                                 \
    float2 nxp = make_float2(0.f, 0.f), nnz = nxp;                            \
    if (act && tpf < TT) {                                                    \
      nxp = *(const float2*)(xp_base + bbase + (size_t)tpf * HH + s0);        \
      nnz = *(const float2*)(noise + bbase + (size_t)tpf * HH + s0);          \
    }                                                                         \
    const f4* h4 = (const f4*)h_lds;                                          \
    f4 acc0 = {0.f, 0.f, 0.f, 0.f};                                           \
    f4 acc1 = {0.f, 0.f, 0.f, 0.f};                                           \
    _Pragma("unroll") for (int j = 0; j < 25; ++j) {                          \
      f4 hv = h4[j]; /* uniform-address broadcast read */                     \
      acc0 = __builtin_elementwise_fma(w0[j], hv, acc0);                      \
      acc1 = __builtin_elementwise_fma(w1[j], hv, acc1);                      \
    }                                                                         \
    float d0 = (acc0.x + acc0.y) + (acc0.z + acc0.w);                         \
    float d1 = (acc1.x + acc1.y) + (acc1.z + acc1.w);                         \
    ahx = fmaf(0.1f, (d0 + XP.x) - ahx, ahx);                                 \
    ahy = fmaf(0.1f, (d1 + XP.y) - ahy, ahy);                                 \
    float e0 = __expf(-2.f * ahx);                                            \
    float e1 = __expf(-2.f * ahy);                                            \
    float h0 = (ahx > 0.f) ? (1.f - e0) * __builtin_amdgcn_rcpf(1.f + e0)     \
                           : 0.f;                                             \
    float h1 = (ahy > 0.f) ? (1.f - e1) * __builtin_amdgcn_rcpf(1.f + e1)     \
                           : 0.f;                                             \
    h0 += NZ.x;                                                               \
    h1 += NZ.y;                                                               \
    /* all h4 reads above precede this write in wave program order */         \
    if (act) {                                                                \
      *(float2*)&h_lds[s0] = make_float2(h0, h1);                             \
      *(float2*)(hstore + bbase + (size_t)(tc)*HH + s0) =                     \
          make_float2(h0, h1);                                                \
    }                                                                         \
    /* fused output projection: partials then full-wave xor tree */           \
    float po0 = act ? fmaf(h0, wy00, h1 * wy01) : 0.f;                        \
    float po1 = act ? fmaf(h0, wy10, h1 * wy11) : 0.f;                        \
    po0 += __shfl_xor(po0, 1, 64);                                            \
    po1 += __shfl_xor(po1, 1, 64);                                            \
    po0 += __shfl_xor(po0, 2, 64);                                            \
    po1 += __shfl_xor(po1, 2, 64);                                            \
    po0 += __shfl_xor(po0, 4, 64);                                            \
    po1 += __shfl_xor(po1, 4, 64);                                            \
    po0 += __shfl_xor(po0, 8, 64);                                            \
    po1 += __shfl_xor(po1, 8, 64);                                            \
    po0 += __shfl_xor(po0, 16, 64);                                           \
    po1 += __shfl_xor(po1, 16, 64);                                           \
    po0 += __shfl_xor(po0, 32, 64);                                           \
    po1 += __shfl_xor(po1, 32, 64);                                           \
    if (l == 0) out2[(size_t)b * TT + (tc)] = make_float2(po0, po1);          \
    XP = nxp;                                                                 \
    NZ = nnz;                                                                 \
  }

#pragma unroll 1
  for (int tc = 0; tc < TT; tc += 4) {
    STEP(xpA, nzA, tc);
    STEP(xpB, nzB, tc + 1);
    STEP(xpC, nzC, tc + 2);
    STEP(xpD, nzD, tc + 3);
  }
#undef STEP
}

// ---------------------------------------------------------------------------
// Launch  (k_outproj deleted: output projection fused into k_scan)
// ---------------------------------------------------------------------------
extern "C" void kernel_launch(void* const* d_in, const int* in_sizes, int n_in,
                              void* d_out, int out_size, void* d_ws,
                              size_t ws_size, hipStream_t stream) {
  const float* input = (const float*)d_in[0];  // [B,T,DI]
  const float* noise = (const float*)d_in[1];  // [B,T,H]
  const float* W_x = (const float*)d_in[2];    // [H,DI]
  const float* b_ah = (const float*)d_in[3];   // [H]
  const float* W_h = (const float*)d_in[4];    // [H,H]
  const float* W_y = (const float*)d_in[5];    // [DO,H]
  const float* ah0 = (const float*)d_in[6];    // [H]

  float* out = (float*)d_out;                    // [B,T,DO]
  float* hstore = out + (size_t)BB * TT * DOUT;  // [B,T,H]

  // K1: input projection -> xp staged into hstore region.
  k_inproj<<<BT / 64, 128, 0, stream>>>(input, W_x, b_ah, hstore);

  // K2: barrier-free scan, one wave per batch; writes hstore + out.
  k_scan<<<BB, 64, 0, stream>>>(noise, W_h, ah0, W_y, out, hstore);
}